// Round 1
// baseline (808.059 us; speedup 1.0000x reference)
//
#include <hip/hip_runtime.h>
#include <hip/hip_bf16.h>

#define CIN   64
#define COUT  64
#define IKDIM 128   // CIN * KSIZE
#define HID   32
#define ZD    128
#define KC    1024
#define SPC   64    // T / K
#define TLEN  65536
#define NG    4     // samples per block

__device__ __forceinline__ float bflo(unsigned u) { return __uint_as_float(u << 16); }
__device__ __forceinline__ float bfhi(unsigned u) { return __uint_as_float(u & 0xffff0000u); }

// round-to-nearest-even fp32 -> bf16 (values are finite; NaN path not needed)
__device__ __forceinline__ unsigned f2bf(float f) {
    unsigned u = __float_as_uint(f);
    unsigned r = u + 0x7fffu + ((u >> 16) & 1u);
    return r >> 16;
}

// w2 [8192 rows][32 h] fp32  ->  w2t [16 h-pairs][8192 rows] packed bf16x2
__global__ void cast_w2_kernel(const float* __restrict__ w2, unsigned* __restrict__ w2t) {
    int i  = blockIdx.x * 256 + threadIdx.x;   // 131072 total
    int h2 = i >> 13;
    int r  = i & 8191;
    unsigned a = f2bf(w2[r * HID + 2 * h2]);
    unsigned b = f2bf(w2[r * HID + 2 * h2 + 1]);
    w2t[i] = a | (b << 16);
}

__global__ __launch_bounds__(256, 2)
void hyperconv_kernel(const float* __restrict__ x, const float* __restrict__ z,
                      const float* __restrict__ w1, const float* __restrict__ b1,
                      const float* __restrict__ b2,
                      const float* __restrict__ w3, const float* __restrict__ b3,
                      const float* __restrict__ w4, const float* __restrict__ b4,
                      const unsigned* __restrict__ w2t,
                      float* __restrict__ out)
{
    __shared__ float s_z[NG][ZD];
    __shared__ float s_h1[NG][HID];
    __shared__ float s_h3[NG][HID];
    __shared__ float s_bias[NG][COUT];
    __shared__ __align__(16) unsigned short s_w[NG][IKDIM * COUT];  // bf16 weights

    const int tid = threadIdx.x;
    const int nb  = blockIdx.x;       // 0..2047
    const int n0  = nb * NG;          // first flat sample (b*K + kk)
    const int b   = n0 >> 10;         // / 1024
    const int kk0 = n0 & 1023;

    // ---- Phase A: stage z[b, :, kk0..kk0+3] ----
    #pragma unroll
    for (int i = 0; i < 2; ++i) {
        int idx = tid + i * 256;          // 0..511
        int g = idx >> 7, d = idx & 127;
        s_z[g][d] = z[((size_t)b * ZD + d) * KC + kk0 + g];
    }
    __syncthreads();

    // ---- Phase B: h1 = relu(w1@z+b1), h3 = relu(w3@z+b3) ----
    {
        int g = tid >> 6, u = tid & 63;
        const float* wrow = (u < HID) ? (w1 + u * ZD) : (w3 + (u - HID) * ZD);
        float acc = (u < HID) ? b1[u] : b3[u - HID];
        #pragma unroll
        for (int d4 = 0; d4 < ZD / 4; ++d4) {
            float4 wv = *(const float4*)(wrow + 4 * d4);
            float4 zv = *(const float4*)(&s_z[g][4 * d4]);
            acc += wv.x * zv.x + wv.y * zv.y + wv.z * zv.z + wv.w * zv.w;
        }
        acc = fmaxf(acc, 0.f);
        if (u < HID) s_h1[g][u] = acc; else s_h3[g][u - HID] = acc;
    }
    __syncthreads();

    // ---- Phase C: bias = w4@h3 + b4 ----
    {
        int g = tid >> 6, o = tid & 63;
        float acc = b4[o];
        #pragma unroll
        for (int h4 = 0; h4 < HID / 4; ++h4) {
            float4 wv = *(const float4*)(w4 + o * HID + 4 * h4);
            float4 hv = *(const float4*)(&s_h3[g][4 * h4]);
            acc += wv.x * hv.x + wv.y * hv.y + wv.z * hv.z + wv.w * hv.w;
        }
        s_bias[g][o] = acc;
    }

    // ---- Phase D: W[g][ik*64+co] = b2[r] + sum_h w2[r][h]*h1[g][h], stored bf16 ----
    {
        float h1r[NG][HID];                 // hoist h1 into registers (128 VGPR)
        #pragma unroll
        for (int g = 0; g < NG; ++g)
            #pragma unroll
            for (int h = 0; h < HID; ++h)
                h1r[g][h] = s_h1[g][h];

        for (int rr = 0; rr < 8192 / 256; ++rr) {
            int r = rr * 256 + tid;
            float bb = b2[r];
            float a0 = bb, a1 = bb, a2 = bb, a3 = bb;
            #pragma unroll
            for (int h2 = 0; h2 < HID / 2; ++h2) {
                unsigned u = w2t[h2 * 8192 + r];   // coalesced packed bf16x2
                float lo = bflo(u), hi = bfhi(u);
                a0 += lo * h1r[0][2*h2] + hi * h1r[0][2*h2+1];
                a1 += lo * h1r[1][2*h2] + hi * h1r[1][2*h2+1];
                a2 += lo * h1r[2][2*h2] + hi * h1r[2][2*h2+1];
                a3 += lo * h1r[3][2*h2] + hi * h1r[3][2*h2+1];
            }
            s_w[0][r] = (unsigned short)f2bf(a0);
            s_w[1][r] = (unsigned short)f2bf(a1);
            s_w[2][r] = (unsigned short)f2bf(a2);
            s_w[3][r] = (unsigned short)f2bf(a3);
        }
    }
    __syncthreads();

    // ---- Phase E: y[s,o] = sum_c x_t[c,s]*W[c,o] + x_{t-1}[c,s]*W[c+64,o] + bias[o] ----
    {
        const int g    = tid >> 6;        // wave g <-> sample kk0+g
        const int lane = tid & 63;
        const int s0   = (lane >> 3) << 3;
        const int o0   = (lane & 7) << 3;
        const size_t t0 = (size_t)(kk0 + g) * SPC;
        const float* xbase = x + (size_t)b * CIN * TLEN + t0 + s0;
        const bool has_prev = (t0 + s0) != 0;

        float acc[8][8];
        #pragma unroll
        for (int i = 0; i < 8; ++i)
            #pragma unroll
            for (int j = 0; j < 8; ++j) acc[i][j] = 0.f;

        for (int c = 0; c < CIN; ++c) {
            const float* xc = xbase + (size_t)c * TLEN;
            float4 xa = *(const float4*)xc;
            float4 xb = *(const float4*)(xc + 4);
            float xm1 = has_prev ? xc[-1] : 0.f;
            float xcur[8] = {xa.x, xa.y, xa.z, xa.w, xb.x, xb.y, xb.z, xb.w};
            float xprv[8] = {xm1, xa.x, xa.y, xa.z, xa.w, xb.x, xb.y, xb.z};
            uint4 u0 = *(const uint4*)(&s_w[g][c * COUT + o0]);
            uint4 u1 = *(const uint4*)(&s_w[g][(c + CIN) * COUT + o0]);
            float w0[8]  = {bflo(u0.x), bfhi(u0.x), bflo(u0.y), bfhi(u0.y),
                            bflo(u0.z), bfhi(u0.z), bflo(u0.w), bfhi(u0.w)};
            float w1v[8] = {bflo(u1.x), bfhi(u1.x), bflo(u1.y), bfhi(u1.y),
                            bflo(u1.z), bfhi(u1.z), bflo(u1.w), bfhi(u1.w)};
            #pragma unroll
            for (int si = 0; si < 8; ++si)
                #pragma unroll
                for (int oi = 0; oi < 8; ++oi)
                    acc[si][oi] += xcur[si] * w0[oi] + xprv[si] * w1v[oi];
        }

        float* obase = out + (size_t)b * COUT * TLEN + t0 + s0;
        #pragma unroll
        for (int oi = 0; oi < 8; ++oi) {
            float bv = s_bias[g][o0 + oi];
            float* po = obase + (size_t)(o0 + oi) * TLEN;
            *(float4*)po       = make_float4(acc[0][oi] + bv, acc[1][oi] + bv,
                                             acc[2][oi] + bv, acc[3][oi] + bv);
            *(float4*)(po + 4) = make_float4(acc[4][oi] + bv, acc[5][oi] + bv,
                                             acc[6][oi] + bv, acc[7][oi] + bv);
        }
    }
}

extern "C" void kernel_launch(void* const* d_in, const int* in_sizes, int n_in,
                              void* d_out, int out_size, void* d_ws, size_t ws_size,
                              hipStream_t stream) {
    const float* x  = (const float*)d_in[0];
    const float* z  = (const float*)d_in[1];
    const float* w1 = (const float*)d_in[2];
    const float* b1 = (const float*)d_in[3];
    const float* w2 = (const float*)d_in[4];
    const float* b2 = (const float*)d_in[5];
    const float* w3 = (const float*)d_in[6];
    const float* b3 = (const float*)d_in[7];
    const float* w4 = (const float*)d_in[8];
    const float* b4 = (const float*)d_in[9];
    float* out = (float*)d_out;
    unsigned* w2t = (unsigned*)d_ws;   // 512 KB scratch: transposed packed-bf16 w2

    cast_w2_kernel<<<512, 256, 0, stream>>>(w2, w2t);
    hyperconv_kernel<<<2048, 256, 0, stream>>>(x, z, w1, b1, b2, w3, b3, w4, b4, w2t, out);
}

// Round 3
// 365.601 us; speedup vs baseline: 2.2102x; 2.2102x over previous
//
#include <hip/hip_runtime.h>
#include <hip/hip_bf16.h>

#define CIN   64
#define COUT  64
#define HID   32
#define ZD    128
#define KC    1024
#define SPC   64
#define TLEN  65536

typedef __attribute__((ext_vector_type(8))) short bf16x8;
typedef __attribute__((ext_vector_type(4))) float f32x4;

__device__ __forceinline__ unsigned f2bf(float f) {
    unsigned u = __float_as_uint(f);
    unsigned r = u + 0x7fffu + ((u >> 16) & 1u);
    return r >> 16;
}
__device__ __forceinline__ unsigned pk2(float a, float b) {
    return f2bf(a) | (f2bf(b) << 16);
}

// w2 [8192 r][32 h] fp32 -> w2b [8192 r][16 packed bf16x2]  (B-fragment friendly)
__global__ void cast_w2_kernel(const float* __restrict__ w2, unsigned* __restrict__ w2b) {
    int i  = blockIdx.x * 256 + threadIdx.x;   // 131072
    int r  = i >> 4;
    int hp = i & 15;
    w2b[i] = pk2(w2[r * HID + 2 * hp], w2[r * HID + 2 * hp + 1]);
}

__global__ __launch_bounds__(256, 2)
void hyperconv_mfma(const float* __restrict__ x, const float* __restrict__ z,
                    const float* __restrict__ w1, const float* __restrict__ b1,
                    const float* __restrict__ b2,
                    const float* __restrict__ w3, const float* __restrict__ b3,
                    const float* __restrict__ w4, const float* __restrict__ b4,
                    const uint4* __restrict__ w2b,   // [8192 r][4] uint4
                    float* __restrict__ out)
{
    __shared__ float s_z[4][ZD];
    __shared__ float s_h3[4][HID];
    __shared__ float s_bias[4][COUT];
    __shared__ __align__(16) short s_h1b[4][HID];
    __shared__ __align__(16) short s_w[4][8192];   // per-sample W, layout [ks][q][o][j]

    const int tid  = threadIdx.x;
    const int w    = tid >> 6;        // wave id == sample-in-block
    const int lane = tid & 63;
    const int l15  = lane & 15;
    const int q    = lane >> 4;
    const int n0   = blockIdx.x * 4;
    const int b    = n0 >> 10;
    const int kk0  = n0 & 1023;

    // ---- Phase A: stage z[b, :, kk0..kk0+3] ----
    #pragma unroll
    for (int i = 0; i < 2; ++i) {
        int idx = tid + i * 256;
        int g = idx >> 7, d = idx & 127;
        s_z[g][d] = z[((size_t)b * ZD + d) * KC + kk0 + g];
    }
    __syncthreads();

    // ---- Phase B: h1 (bf16) and h3 ----
    {
        int g = tid >> 6, u = tid & 63;
        const float* wrow = (u < HID) ? (w1 + u * ZD) : (w3 + (u - HID) * ZD);
        float acc = (u < HID) ? b1[u] : b3[u - HID];
        #pragma unroll
        for (int d4 = 0; d4 < ZD / 4; ++d4) {
            float4 wv = *(const float4*)(wrow + 4 * d4);
            float4 zv = *(const float4*)(&s_z[g][4 * d4]);
            acc += wv.x * zv.x + wv.y * zv.y + wv.z * zv.z + wv.w * zv.w;
        }
        acc = fmaxf(acc, 0.f);
        if (u < HID) s_h1b[g][u] = (short)f2bf(acc);
        else         s_h3[g][u - HID] = acc;
    }
    __syncthreads();

    // ---- Phase C: bias = w4@h3 + b4 (wave g computes s_bias[g]) ----
    {
        int g = tid >> 6, o = tid & 63;
        float acc = b4[o];
        #pragma unroll
        for (int h4 = 0; h4 < HID / 4; ++h4) {
            float4 wv = *(const float4*)(w4 + o * HID + 4 * h4);
            float4 hv = *(const float4*)(&s_h3[g][4 * h4]);
            acc += wv.x * hv.x + wv.y * hv.y + wv.z * hv.z + wv.w * hv.w;
        }
        s_bias[g][o] = acc;
    }

    // ---- Phase D: W = w2 @ h1 + b2 via MFMA; wave w covers r in [w*2048, w*2048+2048) ----
    {
        bf16x8 afrag = *(const bf16x8*)&s_h1b[l15 & 3][q * 8];   // A[m=sample][k=h]
        const int rb = w * 2048;                                 // ks slot == w
        #pragma unroll
        for (int ntl = 0; ntl < 4; ++ntl) {
            #pragma unroll
            for (int q2 = 0; q2 < 4; ++q2) {
                float cv[4][8];
                #pragma unroll
                for (int jj = 0; jj < 8; ++jj) {
                    int r = rb + 512 * q2 + 64 * jj + 16 * ntl + l15;
                    bf16x8 bfrag = __builtin_bit_cast(bf16x8, w2b[r * 4 + q]); // B[k=h][n=r]
                    f32x4 c = __builtin_amdgcn_mfma_f32_16x16x32_bf16(
                        afrag, bfrag, (f32x4){0.f, 0.f, 0.f, 0.f}, 0, 0, 0);
                    float b2v = b2[r];
                    #pragma unroll
                    for (int reg = 0; reg < 4; ++reg) cv[reg][jj] = c[reg] + b2v;
                }
                if (lane < 16) {   // C rows 0..3 = real samples live in quad 0
                    #pragma unroll
                    for (int reg = 0; reg < 4; ++reg) {
                        uint4 res;
                        res.x = pk2(cv[reg][0], cv[reg][1]);
                        res.y = pk2(cv[reg][2], cv[reg][3]);
                        res.z = pk2(cv[reg][4], cv[reg][5]);
                        res.w = pk2(cv[reg][6], cv[reg][7]);
                        *(uint4*)&s_w[reg][rb + 512 * q2 + (16 * ntl + l15) * 8] = res;
                    }
                }
            }
        }
    }
    __syncthreads();

    // ---- Phase E: y = W^T @ xu via MFMA; C[m=o][n=s] ----
    {
        const int t0 = (kk0 + w) * SPC;
        const float* xb = x + (size_t)b * CIN * TLEN;
        f32x4 acc[4][4];
        #pragma unroll
        for (int i = 0; i < 4; ++i)
            #pragma unroll
            for (int j = 0; j < 4; ++j) acc[i][j] = (f32x4){0.f, 0.f, 0.f, 0.f};

        for (int ks = 0; ks < 4; ++ks) {
            bf16x8 afr[4];
            #pragma unroll
            for (int ot = 0; ot < 4; ++ot)   // A[m=o][k=ik] from s_w
                afr[ot] = *(const bf16x8*)&s_w[w][ks * 2048 + q * 512 + (16 * ot + l15) * 8];

            const int koff = (ks >= 2) ? -1 : 0;   // ik>=64 -> x[t-1]
            const int c0 = (ks & 1) * 32 + 8 * q;
            bf16x8 bfr[4];
            #pragma unroll
            for (int st = 0; st < 4; ++st) {       // B[k=ik][n=s] from x
                int t = t0 + 16 * st + l15 + koff;
                int tc = t < 0 ? 0 : t;
                float v[8];
                #pragma unroll
                for (int j = 0; j < 8; ++j)
                    v[j] = xb[(size_t)(c0 + j) * TLEN + tc];
                if (t < 0) {
                    #pragma unroll
                    for (int j = 0; j < 8; ++j) v[j] = 0.f;
                }
                uint4 p;
                p.x = pk2(v[0], v[1]); p.y = pk2(v[2], v[3]);
                p.z = pk2(v[4], v[5]); p.w = pk2(v[6], v[7]);
                bfr[st] = __builtin_bit_cast(bf16x8, p);
            }

            #pragma unroll
            for (int ot = 0; ot < 4; ++ot)
                #pragma unroll
                for (int st = 0; st < 4; ++st)
                    acc[ot][st] = __builtin_amdgcn_mfma_f32_16x16x32_bf16(
                        afr[ot], bfr[st], acc[ot][st], 0, 0, 0);
        }

        // stores: row=o, col=s -> 16 consecutive t per quad, coalesced
        float* ob = out + (size_t)b * COUT * TLEN;
        #pragma unroll
        for (int ot = 0; ot < 4; ++ot) {
            f32x4 bv = *(const f32x4*)&s_bias[w][16 * ot + 4 * q];
            #pragma unroll
            for (int st = 0; st < 4; ++st) {
                int t = t0 + 16 * st + l15;
                #pragma unroll
                for (int reg = 0; reg < 4; ++reg)
                    ob[(size_t)(16 * ot + 4 * q + reg) * TLEN + t] = acc[ot][st][reg] + bv[reg];
            }
        }
    }
}

extern "C" void kernel_launch(void* const* d_in, const int* in_sizes, int n_in,
                              void* d_out, int out_size, void* d_ws, size_t ws_size,
                              hipStream_t stream) {
    const float* x  = (const float*)d_in[0];
    const float* z  = (const float*)d_in[1];
    const float* w1 = (const float*)d_in[2];
    const float* b1 = (const float*)d_in[3];
    const float* w2 = (const float*)d_in[4];
    const float* b2 = (const float*)d_in[5];
    const float* w3 = (const float*)d_in[6];
    const float* b3 = (const float*)d_in[7];
    const float* w4 = (const float*)d_in[8];
    const float* b4 = (const float*)d_in[9];
    float* out = (float*)d_out;
    unsigned* w2b = (unsigned*)d_ws;   // 512 KB scratch

    cast_w2_kernel<<<512, 256, 0, stream>>>(w2, w2b);
    hyperconv_mfma<<<2048, 256, 0, stream>>>(x, z, w1, b1, b2, w3, b3, w4, b4,
                                             (const uint4*)w2b, out);
}